// Round 12
// baseline (15.305 us; speedup 1.0000x reference)
//
#include <hip/hip_runtime.h>

#define NUM_GRAPHS 128
#define NUM_T 64
#define NUM_S 64
#define TPB 8            // thetas per block
#define NTH (NUM_T/TPB)  // 8 theta-octet blocks per graph
#define NROWS 66         // word rows wr = sw+1, sw in [-1,64] -> wr in [0,65]

// Fully fused windowed-sigmoid ECT: centered 1-eval window, quintic
// polynomial sigmoid (no transcendentals), ONE packed ds_add_u32 per pair.
// Grid: (128 graphs) x (8 theta-octets). Block = 512 threads owns the
// disjoint slice out[g][0:64][th*8 : th*8+8] -> plain stores.
//
// w = (nh+1)*31.5, sw = rint(w), d = sw - w in [-0.5, 0.5] ALWAYS:
//   s = sw : z = -6.349*d in [-3.17, 3.17] -> sigma(z) ~= 0.5 + g(d),
//            g(d) = c1*d + c3*d^3 + c5*d^5 (odd quintic, |err| <= 0.0045)
//   s < sw : folds to 0 (err <= 0.040/pt);  s > sw : folds to 1 -> count
// Packed u32 LDS word at [tl][wr], wr = clamp(sw,-1,64)+1 (one ds_add_u32):
//   bits[ 0:22) bin(s=wr-1) x 2^12  (sum <= 900*3932 = 3.54M < 2^22, no carry)
//   bits[22:32) count, suffix from s=wr (<= ~900 < 1023; word < 2^32)
// inc = (u32)fmaf(g, 4096, 2^22 + 2048.5) -- count bit rides in the constant
// (exact: value < 2^23). Rows 0 / 65 are natural discards for the clamps.
// out[s] = bin(w[s+1])*2^-12 + prefix_{wr<=s} cnt(w[wr]).
__global__ __launch_bounds__(512, 8) void ect_fused_kernel(
    const float2* __restrict__ x, const float* __restrict__ v,
    const int* __restrict__ batch, int n, float* __restrict__ out)
{
    constexpr float C1 = 1.569095f;   // interp of 0.5*tanh(3.1746 d)
    constexpr float C3 = -4.224718f;
    constexpr float C5 = 6.509020f;
    constexpr float SCALE     = 4096.0f;               // 2^12
    constexpr float PACKBIAS  = 4196352.5f;            // 2^22 + 2^11 + 0.5
    constexpr float INV_SCALE = 2.44140625e-04f;       // 2^-12
    constexpr unsigned M22    = 0x3FFFFFu;

    const int g   = blockIdx.x;
    const int th  = blockIdx.y;
    const int tid = (int)threadIdx.x;
    const int lane = tid & 63;
    const int tl   = lane & 7;    // theta column within octet
    const int pg   = lane >> 3;   // point-group 0..7
    const int wv   = tid >> 6;    // wave id 0..7

    __shared__ unsigned sm_w[TPB * NROWS];     // [tl][wr] {bin:22, cnt:10}
    __shared__ unsigned sm_pref[NUM_S * TPB];  // [s][col] inclusive cnt prefix
    __shared__ unsigned sm_seg[8 * TPB];       // per-8-row-segment sums
    __shared__ int sh_cnt[4];

    for (int i = tid; i < TPB * NROWS; i += 512) sm_w[i] = 0u;
    if (tid < 4) sh_cnt[tid] = 0;
    __syncthreads();

    // ---- lane-parallel segment search: loA = #(batch < g), loB = #(< g+1)
    const int S = (n + 511) / 512;              // probe stride
    {
        const int pos = tid * S;
        const int val = (pos < n) ? batch[pos] : 0x7fffffff;
        const unsigned long long mA = __ballot(val < g);
        const unsigned long long mB = __ballot(val < g + 1);
        if ((tid & 63) == 0) {
            atomicAdd(&sh_cnt[0], (int)__popcll(mA));
            atomicAdd(&sh_cnt[1], (int)__popcll(mB));
        }
    }
    __syncthreads();
    const int cA = sh_cnt[0], cB = sh_cnt[1];
    const int baseA = (cA - 1) * S, baseB = (cB - 1) * S;
    {
        int a2 = 0, b2 = 0;
        for (int j = tid + 1; j <= S; j += 512) {
            if (cA >= 1) {
                const int p  = baseA + j;
                const int vv = (p < n) ? batch[p] : 0x7fffffff;
                a2 += (vv < g);
            }
            if (cB >= 1) {
                const int p  = baseB + j;
                const int vv = (p < n) ? batch[p] : 0x7fffffff;
                b2 += (vv < g + 1);
            }
        }
        const unsigned long long mA = __ballot(a2 != 0);
        const unsigned long long mB = __ballot(b2 != 0);
        if ((tid & 63) == 0) {
            atomicAdd(&sh_cnt[2], (int)__popcll(mA));
            atomicAdd(&sh_cnt[3], (int)__popcll(mB));
        }
    }
    __syncthreads();
    const int loA = (cA == 0) ? 0 : baseA + 1 + sh_cnt[2];
    const int loB = (cB == 0) ? 0 : baseB + 1 + sh_cnt[3];

    // ---- main point loop: 8 points x 8 thetas per wave-iteration
    const int t = th * TPB + tl;
    const float w0t = 31.5f * v[2 * t];
    const float w1t = 31.5f * v[2 * t + 1];
    const int tlBase1 = tl * NROWS + 1;   // idx = tlBase1 + sw_clamped

    for (int ibase = loA + wv * 8; ibase < loB; ibase += 64) {
        const int j   = ibase + pg;
        const int jc  = min(j, loB - 1);
        const float2 p = x[jc];                       // coalesced 64B / wave
        float w = fmaf(p.x, w0t, fmaf(p.y, w1t, 31.5f)); // (nh+1)*31.5
        if (j >= loB) w = 3.2e6f;                     // poison -> row 65
        const float ucf = rintf(w);                   // sw (exact, |w|<2^24)
        const float d   = ucf - w;                    // in [-0.5, 0.5] ALWAYS
        const float t2 = d * d;
        const float pq = fmaf(fmaf(C5, t2, C3), t2, C1);
        const float gv = pq * d;                      // in [-0.46, 0.46]
        const unsigned inc = (unsigned)fmaf(gv, SCALE, PACKBIAS);
        const int swi = max(min((int)ucf, 64), -1);   // addressing clamp only
        atomicAdd(&sm_w[tlBase1 + swi], inc);         // native ds_add_u32
    }
    __syncthreads();

    // ---- Phase A: per-col inclusive prefix of cnt field over wr = 0..63
    if (tid < 64) {
        const int seg = tid >> 3, col = tid & 7;
        const int cb  = col * NROWS;
        unsigned run = 0;
        #pragma unroll
        for (int k = 0; k < 8; ++k) {
            const int wr = (seg << 3) + k;
            run += sm_w[cb + wr] >> 22;
            sm_pref[(wr << 3) + col] = run;           // inclusive within seg
        }
        sm_seg[(seg << 3) + col] = run;
    }
    __syncthreads();

    // ---- Phase B: combine + store. out[s] = bin(wr=s+1)*eps + cnt_prefix(s)
    const int s   = tid >> 3;
    const int col = tid & 7;
    const int seg_i = s >> 3;
    unsigned off = 0;
    #pragma unroll
    for (int q = 0; q < 7; ++q)
        if (q < seg_i) off += sm_seg[(q << 3) + col];

    const unsigned bins = sm_w[col * NROWS + (s + 1)] & M22;

    out[((size_t)g * NUM_S + s) * NUM_T + th * TPB + col] =
        (float)(off + sm_pref[(s << 3) + col]) + (float)bins * INV_SCALE;
}

extern "C" void kernel_launch(void* const* d_in, const int* in_sizes, int n_in,
                              void* d_out, int out_size, void* d_ws, size_t ws_size,
                              hipStream_t stream) {
    const float2* x   = (const float2*)d_in[0];   // [N,2] f32
    const float*  v   = (const float*)d_in[1];    // [64,2] f32
    const int*    bat = (const int*)d_in[3];      // [N] i32 (sorted)
    float* out = (float*)d_out;                   // [128,64,64] f32
    const int n = in_sizes[3];

    ect_fused_kernel<<<dim3(NUM_GRAPHS, NTH), 512, 0, stream>>>(x, v, bat, n, out);
}

// Round 13
// 13.968 us; speedup vs baseline: 1.0956x; 1.0956x over previous
//
#include <hip/hip_runtime.h>

#define NUM_GRAPHS 128
#define NUM_T 64
#define NUM_S 64
#define TPB 8            // thetas per block
#define NTH (NUM_T/TPB)  // 8 theta-octet blocks per graph
#define NROWS 66         // word rows wr = sw+1, sw in [-1,64] -> wr in [0,65]

// Fully fused windowed-sigmoid ECT: centered 1-eval window, quintic
// polynomial sigmoid (no transcendentals), one ds_add_u64 per pair.
// Grid: (128 graphs) x (8 theta-octets). Block = 512 threads owns the
// disjoint slice out[g][0:64][th*8 : th*8+8] -> plain stores.
//
// w = (nh+1)*31.5, sw = rint(w), d = sw - w in [-0.5, 0.5] ALWAYS:
//   s = sw : z = -6.349*d in [-3.17, 3.17] -> sigma(z) ~= 0.5 + g(d),
//            g(d) = c1*d + c3*d^3 + c5*d^5 (odd quintic, |err| <= 0.0045)
//   s < sw : folds to 0 (err <= 0.040/pt);  s > sw : folds to 1 -> count
// LDS word at [tl][wr], wr = clamp(sw,-1,64)+1 (one ds_add_u64):
//   lo 32b: bin(s=wr-1) x 2^20  (u0 < 2^21, sum <= 900*2^21 < 2^32)
//   hi 32b: count, suffix from s=wr
// Rows 0 (bin s=-1) and 65 (count from s=65) are natural discards, so the
// clamped lanes' poly value never matters. [tl][wr] layout: atomic bank =
// (4*tl + 2*wr)%32 -> same-tl lanes conflict only at wr==wr' (mod 16).
// NOTE (R12 post-mortem): a packed ds_add_u32 variant REGRESSED (13.8->15.3);
// LDS atomic cost is per-instruction, not per-byte — keep the u64 form.
__global__ __launch_bounds__(512, 8) void ect_fused_kernel(
    const float2* __restrict__ x, const float* __restrict__ v,
    const int* __restrict__ batch, int n, float* __restrict__ out)
{
    constexpr float C1 = 1.569095f;   // interp of 0.5*tanh(3.1746 d)
    constexpr float C3 = -4.224718f;
    constexpr float C5 = 6.509020f;
    constexpr float SCALE     = 1048576.0f;            // 2^20
    constexpr float HALFBIAS  = 524288.5f;             // 0.5*2^20 + 0.5 (round)
    constexpr float INV_SCALE = 9.5367431640625e-07f;  // 2^-20

    const int g   = blockIdx.x;
    const int th  = blockIdx.y;
    const int tid = (int)threadIdx.x;
    const int lane = tid & 63;
    const int tl   = lane & 7;    // theta column within octet
    const int pg   = lane >> 3;   // point-group 0..7
    const int wv   = tid >> 6;    // wave id 0..7

    __shared__ unsigned long long sm_w[TPB * NROWS];  // [tl][wr] {lo:bin,hi:cnt}
    __shared__ unsigned sm_pref[NUM_S * TPB];         // [s][col] incl. prefix
    __shared__ unsigned sm_seg[8 * TPB];              // per-8-row-segment sums
    __shared__ int sh_cnt[4];

    for (int i = tid; i < TPB * NROWS; i += 512) sm_w[i] = 0ull;
    if (tid < 4) sh_cnt[tid] = 0;
    __syncthreads();

    // ---- lane-parallel segment search: loA = #(batch < g), loB = #(< g+1)
    const int S = (n + 511) / 512;              // probe stride
    {
        const int pos = tid * S;
        const int val = (pos < n) ? batch[pos] : 0x7fffffff;
        const unsigned long long mA = __ballot(val < g);
        const unsigned long long mB = __ballot(val < g + 1);
        if ((tid & 63) == 0) {
            atomicAdd(&sh_cnt[0], (int)__popcll(mA));
            atomicAdd(&sh_cnt[1], (int)__popcll(mB));
        }
    }
    __syncthreads();
    const int cA = sh_cnt[0], cB = sh_cnt[1];
    const int baseA = (cA - 1) * S, baseB = (cB - 1) * S;
    {
        int a2 = 0, b2 = 0;
        for (int j = tid + 1; j <= S; j += 512) {
            if (cA >= 1) {
                const int p  = baseA + j;
                const int vv = (p < n) ? batch[p] : 0x7fffffff;
                a2 += (vv < g);
            }
            if (cB >= 1) {
                const int p  = baseB + j;
                const int vv = (p < n) ? batch[p] : 0x7fffffff;
                b2 += (vv < g + 1);
            }
        }
        const unsigned long long mA = __ballot(a2 != 0);
        const unsigned long long mB = __ballot(b2 != 0);
        if ((tid & 63) == 0) {
            atomicAdd(&sh_cnt[2], (int)__popcll(mA));
            atomicAdd(&sh_cnt[3], (int)__popcll(mB));
        }
    }
    __syncthreads();
    const int loA = (cA == 0) ? 0 : baseA + 1 + sh_cnt[2];
    const int loB = (cB == 0) ? 0 : baseB + 1 + sh_cnt[3];

    // ---- main point loop: 8 points x 8 thetas per wave-iteration
    const int t = th * TPB + tl;
    const float w0t = 31.5f * v[2 * t];
    const float w1t = 31.5f * v[2 * t + 1];
    const int tlBase1 = tl * NROWS + 1;   // hoisted: idx = tlBase1 + sw_clamped

    for (int ibase = loA + wv * 8; ibase < loB; ibase += 64) {
        const int j   = ibase + pg;
        const int jc  = min(j, loB - 1);
        const float2 p = x[jc];                       // coalesced 64B / wave
        float w = fmaf(p.x, w0t, fmaf(p.y, w1t, 31.5f)); // (nh+1)*31.5
        if (j >= loB) w = 3.2e6f;                     // poison -> row 65
        const float ucf = rintf(w);                   // sw (exact, |w|<2^24)
        const float d   = ucf - w;                    // in [-0.5, 0.5] ALWAYS
        // sigma - 0.5 ~= g(d), odd quintic (no exp2/rcp; max err 0.0045)
        const float t2 = d * d;
        const float pq = fmaf(fmaf(C5, t2, C3), t2, C1);
        const float gv = pq * d;                      // in [-0.46, 0.46]
        const unsigned u0 = (unsigned)fmaf(gv, SCALE, HALFBIAS);
        const int swi = max(min((int)ucf, 64), -1);   // addressing clamp only
        atomicAdd(&sm_w[tlBase1 + swi],
                  (unsigned long long)u0 | (1ULL << 32));
    }
    __syncthreads();

    // ---- Phase A: per-col inclusive prefix of cnt (hi word) over wr = 0..63
    if (tid < 64) {
        const int seg = tid >> 3, col = tid & 7;
        const int cb  = col * NROWS;
        unsigned run = 0;
        #pragma unroll
        for (int k = 0; k < 8; ++k) {
            const int wr = (seg << 3) + k;
            run += (unsigned)(sm_w[cb + wr] >> 32);
            sm_pref[(wr << 3) + col] = run;           // inclusive within seg
        }
        sm_seg[(seg << 3) + col] = run;
    }
    __syncthreads();

    // ---- Phase B: combine + store. out[s] = bins(wr=s+1)*eps + cnt_prefix(s)
    const int s   = tid >> 3;
    const int col = tid & 7;
    const int seg_i = s >> 3;
    unsigned off = 0;
    #pragma unroll
    for (int q = 0; q < 7; ++q)
        if (q < seg_i) off += sm_seg[(q << 3) + col];

    const unsigned bins = (unsigned)sm_w[col * NROWS + (s + 1)];

    out[((size_t)g * NUM_S + s) * NUM_T + th * TPB + col] =
        (float)(off + sm_pref[(s << 3) + col]) + (float)bins * INV_SCALE;
}

extern "C" void kernel_launch(void* const* d_in, const int* in_sizes, int n_in,
                              void* d_out, int out_size, void* d_ws, size_t ws_size,
                              hipStream_t stream) {
    const float2* x   = (const float2*)d_in[0];   // [N,2] f32
    const float*  v   = (const float*)d_in[1];    // [64,2] f32
    const int*    bat = (const int*)d_in[3];      // [N] i32 (sorted)
    float* out = (float*)d_out;                   // [128,64,64] f32
    const int n = in_sizes[3];

    ect_fused_kernel<<<dim3(NUM_GRAPHS, NTH), 512, 0, stream>>>(x, v, bat, n, out);
}